// Round 2
// baseline (1167.385 us; speedup 1.0000x reference)
//
#include <hip/hip_runtime.h>
#include <cstdint>
#include <cstddef>

// Problem dims (fixed by reference)
#define B_  8
#define S_  1024
#define H_  2048
#define NH_ 16
#define DK_ 128
#define M_  (B_ * S_)   // 8192 rows
#define K_  H_          // 2048

typedef __attribute__((ext_vector_type(4))) float  float4v;
typedef __attribute__((ext_vector_type(8))) short  short8v;
typedef __attribute__((ext_vector_type(4))) short  short4v;

__device__ __forceinline__ unsigned short f2bf(float x) {
  union { float f; unsigned u; } un; un.f = x;
  unsigned r = un.u + 0x7FFFu + ((un.u >> 16) & 1u);  // RNE
  return (unsigned short)(r >> 16);
}

// async global->LDS, 16B per lane; LDS dest is wave-uniform base (+lane*16 in HW)
#define GLDS16(gp, lp) __builtin_amdgcn_global_load_lds( \
    (const __attribute__((address_space(1))) void*)(gp), \
    (__attribute__((address_space(3))) void*)(lp), 16, 0, 0)

// DPP row_ror add: x += rotate_within_16lane_row(x, r). Pure VALU (no LDS pipe).
template <int R>
__device__ __forceinline__ float dpp_ror_add(float x) {
  int xi = __builtin_bit_cast(int, x);
  int yi = __builtin_amdgcn_update_dpp(0, xi, 0x120 | R, 0xF, 0xF, false);
  return x + __builtin_bit_cast(float, yi);
}

// ---------------------------------------------------------------- cast x -> bf16
__global__ __launch_bounds__(256) void cast_x_kernel(const float* __restrict__ x,
                                                     short* __restrict__ xb) {
  const int i = blockIdx.x * 256 + threadIdx.x;   // float4 index
  float4v v = *(const float4v*)(x + (size_t)i * 4);
  short4v o;
  o[0] = (short)f2bf(v[0]); o[1] = (short)f2bf(v[1]);
  o[2] = (short)f2bf(v[2]); o[3] = (short)f2bf(v[3]);
  *(short4v*)(xb + (size_t)i * 4) = o;
}

// ---------------------------------------------- transpose+cast weights: T[n][k] = W[k][n]
__global__ __launch_bounds__(256) void transpose_cast_kernel(
    const float* __restrict__ W0, const float* __restrict__ W1,
    const float* __restrict__ W2, const float* __restrict__ W3,
    short* __restrict__ T0, short* __restrict__ T1,
    short* __restrict__ T2, short* __restrict__ T3) {
  __shared__ float tile[32][33];
  const float* W; short* T;
  switch (blockIdx.z) {
    case 0:  W = W0; T = T0; break;
    case 1:  W = W1; T = T1; break;
    case 2:  W = W2; T = T2; break;
    default: W = W3; T = T3; break;
  }
  const int t  = threadIdx.x;
  const int r  = t >> 3;          // 0..31
  const int c4 = (t & 7) * 4;     // 0,4,..28
  const int r0 = blockIdx.y * 32, c0 = blockIdx.x * 32;

  float4v v = *(const float4v*)(W + (size_t)(r0 + r) * K_ + c0 + c4);
  tile[r][c4 + 0] = v[0]; tile[r][c4 + 1] = v[1];
  tile[r][c4 + 2] = v[2]; tile[r][c4 + 3] = v[3];
  __syncthreads();
  short4v o;
#pragma unroll
  for (int j = 0; j < 4; ++j) o[j] = (short)f2bf(tile[c4 + j][r]);
  *(short4v*)(T + (size_t)(c0 + r) * K_ + r0 + c4) = o;
}

// ---------------------------------------------------------------- bf16 MFMA GEMM
// C[m][n] = sum_k A[m][k] * Bt[n][k] (m97 structure: 128^2 tile, BK=32,
// global_load_lds width 16, 2x2 waves x 4x4 16x16x32 frags).
// QFI=true: Bt has 6144 rows = [Wq^T | Wf^T | Wi^T]; epilogue by n0 segment:
//   seg0: q = swish(acc)*DK^-0.5 -> C0   seg1: a = sigmoid(acc) -> C1   seg2: acc -> C2
// QFI=false: identity -> C0.
template <bool QFI>
__global__ __launch_bounds__(256) void gemm_bt(const short* __restrict__ A,
                                               const short* __restrict__ Bt,
                                               float* __restrict__ C0,
                                               float* __restrict__ C1,
                                               float* __restrict__ C2) {
  __shared__ __align__(16) short Al[128 * 32];
  __shared__ __align__(16) short Bl[128 * 32];
  const int t    = threadIdx.x;
  const int wave = t >> 6;
  const int lane = t & 63;
  const int wr   = wave >> 1, wc = wave & 1;       // 2x2 wave grid, 64x64 each
  const int m0   = blockIdx.y * 128, n0 = blockIdx.x * 128;
  const int l15  = lane & 15, l4 = lane >> 4;

  float4v acc[4][4];
#pragma unroll
  for (int m = 0; m < 4; ++m)
#pragma unroll
    for (int n = 0; n < 4; ++n) acc[m][n] = float4v{0.f, 0.f, 0.f, 0.f};

  // staging: chunk c covers LDS bytes [c*16, c*16+16) = row c>>2, k-cols (c&3)*8..+8
  const int c0 = t, c1 = t + 256;
  const size_t rowA0 = (size_t)(m0 + (c0 >> 2)) * K_;
  const size_t rowA1 = (size_t)(m0 + (c1 >> 2)) * K_;
  const size_t rowB0 = (size_t)(n0 + (c0 >> 2)) * K_;
  const size_t rowB1 = (size_t)(n0 + (c1 >> 2)) * K_;
  const int kofs0 = (c0 & 3) * 8, kofs1 = (c1 & 3) * 8;
  char* ldsA0 = (char*)Al + (wave * 64) * 16;
  char* ldsA1 = (char*)Al + (256 + wave * 64) * 16;
  char* ldsB0 = (char*)Bl + (wave * 64) * 16;
  char* ldsB1 = (char*)Bl + (256 + wave * 64) * 16;

  for (int k0 = 0; k0 < K_; k0 += 32) {
    GLDS16(A  + rowA0 + k0 + kofs0, ldsA0);
    GLDS16(A  + rowA1 + k0 + kofs1, ldsA1);
    GLDS16(Bt + rowB0 + k0 + kofs0, ldsB0);
    GLDS16(Bt + rowB1 + k0 + kofs1, ldsB1);
    __syncthreads();   // compiler drains vmcnt before barrier

    short8v af[4], bfr[4];
#pragma unroll
    for (int m = 0; m < 4; ++m)
      af[m] = *(const short8v*)((const char*)Al +
               ((wr * 64 + m * 16 + l15) * 64 + l4 * 16));
#pragma unroll
    for (int n = 0; n < 4; ++n)
      bfr[n] = *(const short8v*)((const char*)Bl +
               ((wc * 64 + n * 16 + l15) * 64 + l4 * 16));
#pragma unroll
    for (int m = 0; m < 4; ++m)
#pragma unroll
      for (int n = 0; n < 4; ++n)
        acc[m][n] = __builtin_amdgcn_mfma_f32_16x16x32_bf16(af[m], bfr[n], acc[m][n], 0, 0, 0);
    __syncthreads();
  }

  // epilogue target + mode (wave-uniform)
  float* C; int ncol0, mode;
  if (QFI) {
    if (n0 < 2048)      { C = C0; ncol0 = n0;        mode = 0; }
    else if (n0 < 4096) { C = C1; ncol0 = n0 - 2048; mode = 1; }
    else                { C = C2; ncol0 = n0 - 4096; mode = 2; }
  } else            { C = C0; ncol0 = n0;        mode = 2; }

#pragma unroll
  for (int m = 0; m < 4; ++m) {
#pragma unroll
    for (int n = 0; n < 4; ++n) {
#pragma unroll
      for (int j = 0; j < 4; ++j) {
        const int row = m0 + wr * 64 + m * 16 + l4 * 4 + j;  // C/D: col=lane&15, row=(lane>>4)*4+reg
        const int col = ncol0 + wc * 64 + n * 16 + l15;
        float val = acc[m][n][j];
        if (mode == 0) {
          const float sg = 1.0f / (1.0f + __expf(-val));
          val = val * sg * 0.088388347648318447f;   // swish * DK^-0.5
        } else if (mode == 1) {
          val = 1.0f / (1.0f + __expf(-val));       // decay a = exp(log_sigmoid(f))
        }
        C[(size_t)row * 2048 + col] = val;
      }
    }
  }
}

// ---------------------------------------------------------------- recurrent scan
// Grid: 512 blocks = (b, head, dv-quarter); 512 threads: grp = t&15 (16 dk-groups
// of 8), dvl = t>>4 (32 dv cols). h[dk][dv] in regs (8/thread). No LDS, no
// barriers: q/a/v read direct from global (L2/L3-resident) with 1-step register
// prefetch; 16-lane reduction via DPP row_ror (pure VALU).
// h = a*(h - v) + v  (== a*h + (1-a)*v);  o = sum_dk q*h.
// NOTE: o aliases v (in-place): v[s] is consumed (data-dep) before o[s] store,
// and only this wave's 16-lane row touches this address. Safe per-thread order.
__global__ __launch_bounds__(512) void scan_kernel(const float* __restrict__ q,
                                                   const float* __restrict__ a,
                                                   const float* __restrict__ v,
                                                   float* __restrict__ o) {
  const int blk = blockIdx.x;
  const int qtr = blk & 3;
  const int h   = (blk >> 2) & (NH_ - 1);
  const int b   = blk >> 6;
  const int t   = threadIdx.x;
  const int grp = t & 15;
  const int dvl = t >> 4;
  const int dk0 = grp * 8;
  const int vcol = qtr * 32 + dvl;
  const size_t base = ((size_t)b * S_) * (size_t)H_ + (size_t)h * DK_;

  float hreg[8];
#pragma unroll
  for (int r = 0; r < 8; ++r) hreg[r] = 0.f;

  // prefetch step 0
  const float* qp0 = q + base + dk0;
  const float* ap0 = a + base + dk0;
  float4v nq0 = *(const float4v*)qp0;
  float4v nq1 = *(const float4v*)(qp0 + 4);
  float4v na0 = *(const float4v*)ap0;
  float4v na1 = *(const float4v*)(ap0 + 4);
  float   nv  = v[base + vcol];

  for (int s = 0; s < S_; ++s) {
    const float4v q0 = nq0, q1 = nq1, a0 = na0, a1 = na1;
    const float vv = nv;
    if (s + 1 < S_) {                       // prefetch next step (overlaps compute)
      const size_t nb = base + (size_t)(s + 1) * H_;
      const float* qp = q + nb + dk0;
      const float* ap = a + nb + dk0;
      nq0 = *(const float4v*)qp;  nq1 = *(const float4v*)(qp + 4);
      na0 = *(const float4v*)ap;  na1 = *(const float4v*)(ap + 4);
      nv  = v[nb + vcol];
    }
    float op0 = 0.f, op1 = 0.f;
#pragma unroll
    for (int c = 0; c < 4; ++c) {
      hreg[c]     = fmaf(a0[c], hreg[c]     - vv, vv);
      op0         = fmaf(q0[c], hreg[c],     op0);
      hreg[4 + c] = fmaf(a1[c], hreg[4 + c] - vv, vv);
      op1         = fmaf(q1[c], hreg[4 + c], op1);
    }
    float op = op0 + op1;
    op = dpp_ror_add<8>(op);
    op = dpp_ror_add<4>(op);
    op = dpp_ror_add<2>(op);
    op = dpp_ror_add<1>(op);
    if (grp == 0) o[base + (size_t)s * H_ + vcol] = op;
  }
}

// ---------------------------------------------------------------- rmsnorm -> bf16
__global__ __launch_bounds__(256) void rmsnorm_kernel(const float* __restrict__ ob,
                                                      const float* __restrict__ gw,
                                                      short* __restrict__ rb) {
  const int row = blockIdx.x;
  const int t   = threadIdx.x;
  const float* xr = ob + (size_t)row * 2048;
  float4v v0 = *(const float4v*)(xr + t * 4);
  float4v v1 = *(const float4v*)(xr + 1024 + t * 4);
  float ss = v0[0]*v0[0] + v0[1]*v0[1] + v0[2]*v0[2] + v0[3]*v0[3]
           + v1[0]*v1[0] + v1[1]*v1[1] + v1[2]*v1[2] + v1[3]*v1[3];
#pragma unroll
  for (int off = 32; off >= 1; off >>= 1) ss += __shfl_xor(ss, off);
  __shared__ float red[4];
  if ((t & 63) == 0) red[t >> 6] = ss;
  __syncthreads();
  const float tot = red[0] + red[1] + red[2] + red[3];
  const float sc  = rsqrtf(tot * (1.0f / 2048.0f) + 1e-5f);
  float4v g0 = *(const float4v*)(gw + t * 4);
  float4v g1 = *(const float4v*)(gw + 1024 + t * 4);
  short4v o0, o1;
#pragma unroll
  for (int j = 0; j < 4; ++j) {
    o0[j] = (short)f2bf(v0[j] * sc * g0[j]);
    o1[j] = (short)f2bf(v1[j] * sc * g1[j]);
  }
  *(short4v*)(rb + (size_t)row * 2048 + t * 4) = o0;
  *(short4v*)(rb + (size_t)row * 2048 + 1024 + t * 4) = o1;
}

// ---------------------------------------------------------------- launch
extern "C" void kernel_launch(void* const* d_in, const int* in_sizes, int n_in,
                              void* d_out, int out_size, void* d_ws, size_t ws_size,
                              hipStream_t stream) {
  const float* x  = (const float*)d_in[0];
  const float* Wq = (const float*)d_in[1];
  const float* Wf = (const float*)d_in[2];
  const float* Wi = (const float*)d_in[3];
  const float* Wo = (const float*)d_in[4];
  const float* gw = (const float*)d_in[5];

  // Workspace layout (256 MiB) with liveness-based aliasing:
  //   xb [0,32M)       bf16 x           -- dead after gemm_qfi; reused as rb
  //   WqT/WfT/WiT      [32M,56M) contiguous => [6144][2048] bf16 for fused gemm
  //   WoT [56M,64M)
  //   qb [64M,128M) ab [128M,192M) fp32
  //   vb [192M,256M)   fp32            -- scan overwrites in place with o (obuf)
  char* ws = (char*)d_ws;
  const size_t MB = 1024 * 1024;
  short* xb   = (short*)(ws);
  short* WqfiT= (short*)(ws + 32 * MB);
  short* WqT  = WqfiT;
  short* WfT  = (short*)(ws + 40 * MB);
  short* WiT  = (short*)(ws + 48 * MB);
  short* WoT  = (short*)(ws + 56 * MB);
  float* qb   = (float*)(ws + 64 * MB);
  float* ab   = (float*)(ws + 128 * MB);
  float* vb   = (float*)(ws + 192 * MB);
  float* obuf = vb;                       // alias: scan writes o over v in place
  short* rb   = xb;                       // alias: xb dead after gemm_qfi
  if (ws_size < 256 * MB) return;

  cast_x_kernel<<<(M_ * K_ / 4) / 256, 256, 0, stream>>>(x, xb);
  transpose_cast_kernel<<<dim3(K_ / 32, K_ / 32, 4), 256, 0, stream>>>(
      Wq, Wf, Wi, Wo, WqT, WfT, WiT, WoT);

  // fused q/f/i projection: N = 6144
  gemm_bt<true><<<dim3(6144 / 128, M_ / 128), 256, 0, stream>>>(
      xb, WqfiT, qb, ab, vb);

  scan_kernel<<<B_ * NH_ * 4, 512, 0, stream>>>(qb, ab, vb, obuf);
  rmsnorm_kernel<<<M_, 256, 0, stream>>>(obuf, gw, rb);

  gemm_bt<false><<<dim3(2048 / 128, M_ / 128), 256, 0, stream>>>(
      rb, WoT, (float*)d_out, nullptr, nullptr);
}

// Round 4
// 885.788 us; speedup vs baseline: 1.3179x; 1.3179x over previous
//
#include <hip/hip_runtime.h>
#include <cstdint>
#include <cstddef>

// Problem dims (fixed by reference)
#define B_  8
#define S_  1024
#define H_  2048
#define NH_ 16
#define DK_ 128
#define M_  (B_ * S_)   // 8192 rows
#define K_  H_          // 2048

typedef __attribute__((ext_vector_type(4))) float  float4v;
typedef __attribute__((ext_vector_type(8))) short  short8v;
typedef __attribute__((ext_vector_type(4))) short  short4v;

__device__ __forceinline__ unsigned short f2bf(float x) {
  union { float f; unsigned u; } un; un.f = x;
  unsigned r = un.u + 0x7FFFu + ((un.u >> 16) & 1u);  // RNE
  return (unsigned short)(r >> 16);
}

// async global->LDS, 16B per lane; LDS dest is wave-uniform base (+lane*16 in HW)
#define GLDS16(gp, lp) __builtin_amdgcn_global_load_lds( \
    (const __attribute__((address_space(1))) void*)(gp), \
    (__attribute__((address_space(3))) void*)(lp), 16, 0, 0)

// DPP row_shr add: accumulate toward higher lane within 16-lane row. Pure VALU.
// After shr4,shr2,shr1 the sum of each 8-lane group lands in its top lane (grp==7).
template <int N>
__device__ __forceinline__ float dpp_shr_add(float x) {
  int xi = __builtin_bit_cast(int, x);
  int yi = __builtin_amdgcn_update_dpp(0, xi, 0x110 | N, 0xF, 0xF, true);
  return x + __builtin_bit_cast(float, yi);
}

// ---------------------------------------------------------------- cast x -> bf16
__global__ __launch_bounds__(256) void cast_x_kernel(const float* __restrict__ x,
                                                     short* __restrict__ xb) {
  const int i = blockIdx.x * 256 + threadIdx.x;   // float4 index
  float4v v = *(const float4v*)(x + (size_t)i * 4);
  short4v o;
  o[0] = (short)f2bf(v[0]); o[1] = (short)f2bf(v[1]);
  o[2] = (short)f2bf(v[2]); o[3] = (short)f2bf(v[3]);
  *(short4v*)(xb + (size_t)i * 4) = o;
}

// ---------------------------------------------- transpose+cast weights: T[n][k] = W[k][n]
__global__ __launch_bounds__(256) void transpose_cast_kernel(
    const float* __restrict__ W0, const float* __restrict__ W1,
    const float* __restrict__ W2, const float* __restrict__ W3,
    short* __restrict__ T0, short* __restrict__ T1,
    short* __restrict__ T2, short* __restrict__ T3) {
  __shared__ float tile[32][33];
  const float* W; short* T;
  switch (blockIdx.z) {
    case 0:  W = W0; T = T0; break;
    case 1:  W = W1; T = T1; break;
    case 2:  W = W2; T = T2; break;
    default: W = W3; T = T3; break;
  }
  const int t  = threadIdx.x;
  const int r  = t >> 3;          // 0..31
  const int c4 = (t & 7) * 4;     // 0,4,..28
  const int r0 = blockIdx.y * 32, c0 = blockIdx.x * 32;

  float4v v = *(const float4v*)(W + (size_t)(r0 + r) * K_ + c0 + c4);
  tile[r][c4 + 0] = v[0]; tile[r][c4 + 1] = v[1];
  tile[r][c4 + 2] = v[2]; tile[r][c4 + 3] = v[3];
  __syncthreads();
  short4v o;
#pragma unroll
  for (int j = 0; j < 4; ++j) o[j] = (short)f2bf(tile[c4 + j][r]);
  *(short4v*)(T + (size_t)(c0 + r) * K_ + r0 + c4) = o;
}

// ---------------------------------------------------------------- bf16 MFMA GEMM
// C[m][n] = sum_k A[m][k] * Bt[n][k] (m97 structure: 128^2 tile, BK=32,
// global_load_lds width 16, 2x2 waves x 4x4 16x16x32 frags).
// QFI=true: Bt has 6144 rows = [Wq^T | Wf^T | Wi^T]; epilogue by n0 segment:
//   seg0: q = swish(acc)*DK^-0.5 -> C0   seg1: a = sigmoid(acc) -> C1   seg2: acc -> C2
// QFI=false: identity -> C0.
template <bool QFI>
__global__ __launch_bounds__(256) void gemm_bt(const short* __restrict__ A,
                                               const short* __restrict__ Bt,
                                               float* __restrict__ C0,
                                               float* __restrict__ C1,
                                               float* __restrict__ C2) {
  __shared__ __align__(16) short Al[128 * 32];
  __shared__ __align__(16) short Bl[128 * 32];
  const int t    = threadIdx.x;
  const int wave = t >> 6;
  const int lane = t & 63;
  const int wr   = wave >> 1, wc = wave & 1;       // 2x2 wave grid, 64x64 each
  const int m0   = blockIdx.y * 128, n0 = blockIdx.x * 128;
  const int l15  = lane & 15, l4 = lane >> 4;

  float4v acc[4][4];
#pragma unroll
  for (int m = 0; m < 4; ++m)
#pragma unroll
    for (int n = 0; n < 4; ++n) acc[m][n] = float4v{0.f, 0.f, 0.f, 0.f};

  // staging: chunk c covers LDS bytes [c*16, c*16+16) = row c>>2, k-cols (c&3)*8..+8
  const int c0 = t, c1 = t + 256;
  const size_t rowA0 = (size_t)(m0 + (c0 >> 2)) * K_;
  const size_t rowA1 = (size_t)(m0 + (c1 >> 2)) * K_;
  const size_t rowB0 = (size_t)(n0 + (c0 >> 2)) * K_;
  const size_t rowB1 = (size_t)(n0 + (c1 >> 2)) * K_;
  const int kofs0 = (c0 & 3) * 8, kofs1 = (c1 & 3) * 8;
  char* ldsA0 = (char*)Al + (wave * 64) * 16;
  char* ldsA1 = (char*)Al + (256 + wave * 64) * 16;
  char* ldsB0 = (char*)Bl + (wave * 64) * 16;
  char* ldsB1 = (char*)Bl + (256 + wave * 64) * 16;

  for (int k0 = 0; k0 < K_; k0 += 32) {
    GLDS16(A  + rowA0 + k0 + kofs0, ldsA0);
    GLDS16(A  + rowA1 + k0 + kofs1, ldsA1);
    GLDS16(Bt + rowB0 + k0 + kofs0, ldsB0);
    GLDS16(Bt + rowB1 + k0 + kofs1, ldsB1);
    __syncthreads();   // compiler drains vmcnt before barrier

    short8v af[4], bfr[4];
#pragma unroll
    for (int m = 0; m < 4; ++m)
      af[m] = *(const short8v*)((const char*)Al +
               ((wr * 64 + m * 16 + l15) * 64 + l4 * 16));
#pragma unroll
    for (int n = 0; n < 4; ++n)
      bfr[n] = *(const short8v*)((const char*)Bl +
               ((wc * 64 + n * 16 + l15) * 64 + l4 * 16));
#pragma unroll
    for (int m = 0; m < 4; ++m)
#pragma unroll
      for (int n = 0; n < 4; ++n)
        acc[m][n] = __builtin_amdgcn_mfma_f32_16x16x32_bf16(af[m], bfr[n], acc[m][n], 0, 0, 0);
    __syncthreads();
  }

  // epilogue target + mode (wave-uniform)
  float* C; int ncol0, mode;
  if (QFI) {
    if (n0 < 2048)      { C = C0; ncol0 = n0;        mode = 0; }
    else if (n0 < 4096) { C = C1; ncol0 = n0 - 2048; mode = 1; }
    else                { C = C2; ncol0 = n0 - 4096; mode = 2; }
  } else            { C = C0; ncol0 = n0;        mode = 2; }

#pragma unroll
  for (int m = 0; m < 4; ++m) {
#pragma unroll
    for (int n = 0; n < 4; ++n) {
#pragma unroll
      for (int j = 0; j < 4; ++j) {
        const int row = m0 + wr * 64 + m * 16 + l4 * 4 + j;  // C/D: col=lane&15, row=(lane>>4)*4+reg
        const int col = ncol0 + wc * 64 + n * 16 + l15;
        float val = acc[m][n][j];
        if (mode == 0) {
          const float sg = 1.0f / (1.0f + __expf(-val));
          val = val * sg * 0.088388347648318447f;   // swish * DK^-0.5
        } else if (mode == 1) {
          val = 1.0f / (1.0f + __expf(-val));       // decay a = exp(log_sigmoid(f))
        }
        C[(size_t)row * 2048 + col] = val;
      }
    }
  }
}

// ---------------------------------------------------------------- recurrent scan v2
// Grid: 512 blocks = (b, head, dv-quarter 32). 256 threads: grp = t&7 (8 dk-groups
// of 16), dvl = t>>3 (32 dv cols). h[dk][dv] in regs (16/thread).
// Time is processed in chunks of T=16 steps, double-buffered in LDS via
// global_load_lds (18KB/buffer: q 8K + a 8K + v 2K, linear layout). Per chunk:
// issue next chunk's loads (async) -> compute 16 steps from current buffer ->
// __syncthreads (drains vmcnt; loads had a full chunk of compute to land).
// LDS q/a reads use quad order j^(grp&3): spreads the 8 groups' simultaneous
// ds_read_b128 to 2-way bank aliasing (free); permutation is identical for
// q/a/hreg so the dk-sum is unaffected.
// 8-lane reduction via DPP row_shr (result lands in grp==7 lane).
// o aliases v in-place: chunk c+1's v loads never touch chunk c's o addresses,
// and the end-of-chunk barrier orders the v[s] load before the o[s] store.
#define TCHUNK 16
#define BUFSZ  18432   // 16*512 (q) + 16*512 (a) + 16*128 (v) bytes

__device__ __forceinline__ void stage_chunk(const float* __restrict__ q,
                                            const float* __restrict__ a,
                                            const float* __restrict__ v,
                                            char* buf, size_t bh, int qtr,
                                            int c0, int wv, int lane) {
  for (int i = wv; i < 18; i += 4) {        // wave-uniform trip count
    if (i < 8) {                            // q: instr i covers steps 2i,2i+1
      const float* g = q + bh + (size_t)(c0 + 2 * i + (lane >> 5)) * H_ + (lane & 31) * 4;
      GLDS16(g, buf + i * 1024);
    } else if (i < 16) {                    // a
      const int k = i - 8;
      const float* g = a + bh + (size_t)(c0 + 2 * k + (lane >> 5)) * H_ + (lane & 31) * 4;
      GLDS16(g, buf + 8192 + k * 1024);
    } else {                                // v: instr k covers steps 8k..8k+7
      const int k = i - 16;
      const float* g = v + bh + (size_t)(c0 + 8 * k + (lane >> 3)) * H_ + qtr * 32 + (lane & 7) * 4;
      GLDS16(g, buf + 16384 + k * 1024);
    }
  }
}

__global__ __launch_bounds__(256) void scan_kernel(const float* __restrict__ q,
                                                   const float* __restrict__ a,
                                                   const float* __restrict__ v,
                                                   float* __restrict__ o) {
  __shared__ __align__(16) char lds[2 * BUFSZ];
  const int blk  = blockIdx.x;
  const int qtr  = blk & 3;
  const int h    = (blk >> 2) & (NH_ - 1);
  const int b    = blk >> 6;
  const int t    = threadIdx.x;
  const int lane = t & 63;
  const int wv   = t >> 6;
  const int grp  = t & 7;
  const int dvl  = t >> 3;
  const int vcol = qtr * 32 + dvl;
  const size_t bh = (size_t)b * S_ * (size_t)H_ + (size_t)h * DK_;

  int qoff[4];
#pragma unroll
  for (int j = 0; j < 4; ++j) qoff[j] = grp * 64 + ((j ^ (grp & 3)) * 16);

  float hreg[16];
#pragma unroll
  for (int r = 0; r < 16; ++r) hreg[r] = 0.f;

  stage_chunk(q, a, v, lds, bh, qtr, 0, wv, lane);
  __syncthreads();   // drains vmcnt for chunk 0

  const int NCH = S_ / TCHUNK;   // 64
  for (int c = 0; c < NCH; ++c) {
    char* cur = lds + (c & 1) * BUFSZ;
    if (c + 1 < NCH)
      stage_chunk(q, a, v, lds + ((c & 1) ^ 1) * BUFSZ, bh, qtr, (c + 1) * TCHUNK, wv, lane);
    const int s0 = c * TCHUNK;
#pragma unroll
    for (int s = 0; s < TCHUNK; ++s) {
      float4v qv[4], av[4];
#pragma unroll
      for (int j = 0; j < 4; ++j) {
        qv[j] = *(const float4v*)(cur + s * 512 + qoff[j]);
        av[j] = *(const float4v*)(cur + 8192 + s * 512 + qoff[j]);
      }
      const float vv = *(const float*)(cur + 16384 + s * 128 + dvl * 4);
      float op = 0.f;
#pragma unroll
      for (int j = 0; j < 4; ++j) {
#pragma unroll
        for (int cc = 0; cc < 4; ++cc) {
          float& hr = hreg[j * 4 + cc];
          hr = fmaf(av[j][cc], hr - vv, vv);   // a*h + (1-a)*v
          op = fmaf(qv[j][cc], hr, op);
        }
      }
      op = dpp_shr_add<4>(op);
      op = dpp_shr_add<2>(op);
      op = dpp_shr_add<1>(op);
      if (grp == 7) o[bh + (size_t)(s0 + s) * H_ + vcol] = op;
    }
    __syncthreads();   // buf consumed; next-chunk loads drained
  }
}

// ---------------------------------------------------------------- rmsnorm -> bf16
__global__ __launch_bounds__(256) void rmsnorm_kernel(const float* __restrict__ ob,
                                                      const float* __restrict__ gw,
                                                      short* __restrict__ rb) {
  const int row = blockIdx.x;
  const int t   = threadIdx.x;
  const float* xr = ob + (size_t)row * 2048;
  float4v v0 = *(const float4v*)(xr + t * 4);
  float4v v1 = *(const float4v*)(xr + 1024 + t * 4);
  float ss = v0[0]*v0[0] + v0[1]*v0[1] + v0[2]*v0[2] + v0[3]*v0[3]
           + v1[0]*v1[0] + v1[1]*v1[1] + v1[2]*v1[2] + v1[3]*v1[3];
#pragma unroll
  for (int off = 32; off >= 1; off >>= 1) ss += __shfl_xor(ss, off);
  __shared__ float red[4];
  if ((t & 63) == 0) red[t >> 6] = ss;
  __syncthreads();
  const float tot = red[0] + red[1] + red[2] + red[3];
  const float sc  = rsqrtf(tot * (1.0f / 2048.0f) + 1e-5f);
  float4v g0 = *(const float4v*)(gw + t * 4);
  float4v g1 = *(const float4v*)(gw + 1024 + t * 4);
  short4v o0, o1;
#pragma unroll
  for (int j = 0; j < 4; ++j) {
    o0[j] = (short)f2bf(v0[j] * sc * g0[j]);
    o1[j] = (short)f2bf(v1[j] * sc * g1[j]);
  }
  *(short4v*)(rb + (size_t)row * 2048 + t * 4) = o0;
  *(short4v*)(rb + (size_t)row * 2048 + 1024 + t * 4) = o1;
}

// ---------------------------------------------------------------- launch
extern "C" void kernel_launch(void* const* d_in, const int* in_sizes, int n_in,
                              void* d_out, int out_size, void* d_ws, size_t ws_size,
                              hipStream_t stream) {
  const float* x  = (const float*)d_in[0];
  const float* Wq = (const float*)d_in[1];
  const float* Wf = (const float*)d_in[2];
  const float* Wi = (const float*)d_in[3];
  const float* Wo = (const float*)d_in[4];
  const float* gw = (const float*)d_in[5];

  // Workspace layout (256 MiB) with liveness-based aliasing:
  //   xb [0,32M)       bf16 x           -- dead after gemm_qfi; reused as rb
  //   WqT/WfT/WiT      [32M,56M) contiguous => [6144][2048] bf16 for fused gemm
  //   WoT [56M,64M)
  //   qb [64M,128M) ab [128M,192M) fp32
  //   vb [192M,256M)   fp32            -- scan overwrites in place with o (obuf)
  char* ws = (char*)d_ws;
  const size_t MB = 1024 * 1024;
  short* xb   = (short*)(ws);
  short* WqfiT= (short*)(ws + 32 * MB);
  short* WqT  = WqfiT;
  short* WfT  = (short*)(ws + 40 * MB);
  short* WiT  = (short*)(ws + 48 * MB);
  short* WoT  = (short*)(ws + 56 * MB);
  float* qb   = (float*)(ws + 64 * MB);
  float* ab   = (float*)(ws + 128 * MB);
  float* vb   = (float*)(ws + 192 * MB);
  float* obuf = vb;                       // alias: scan writes o over v in place
  short* rb   = xb;                       // alias: xb dead after gemm_qfi
  if (ws_size < 256 * MB) return;

  cast_x_kernel<<<(M_ * K_ / 4) / 256, 256, 0, stream>>>(x, xb);
  transpose_cast_kernel<<<dim3(K_ / 32, K_ / 32, 4), 256, 0, stream>>>(
      Wq, Wf, Wi, Wo, WqT, WfT, WiT, WoT);

  // fused q/f/i projection: N = 6144
  gemm_bt<true><<<dim3(6144 / 128, M_ / 128), 256, 0, stream>>>(
      xb, WqfiT, qb, ab, vb);

  scan_kernel<<<B_ * NH_ * 4, 256, 0, stream>>>(qb, ab, vb, obuf);
  rmsnorm_kernel<<<M_, 256, 0, stream>>>(obuf, gw, rb);

  gemm_bt<false><<<dim3(2048 / 128, M_ / 128), 256, 0, stream>>>(
      rb, WoT, (float*)d_out, nullptr, nullptr);
}

// Round 6
// 747.516 us; speedup vs baseline: 1.5617x; 1.1850x over previous
//
#include <hip/hip_runtime.h>
#include <cstdint>
#include <cstddef>

// Problem dims (fixed by reference)
#define B_  8
#define S_  1024
#define H_  2048
#define NH_ 16
#define DK_ 128
#define M_  (B_ * S_)   // 8192 rows
#define K_  H_          // 2048

typedef __attribute__((ext_vector_type(4))) float  float4v;
typedef __attribute__((ext_vector_type(8))) short  short8v;
typedef __attribute__((ext_vector_type(4))) short  short4v;

__device__ __forceinline__ unsigned short f2bf(float x) {
  union { float f; unsigned u; } un; un.f = x;
  unsigned r = un.u + 0x7FFFu + ((un.u >> 16) & 1u);  // RNE
  return (unsigned short)(r >> 16);
}

// async global->LDS, 16B per lane; LDS dest is wave-uniform base (+lane*16 in HW)
#define GLDS16(gp, lp) __builtin_amdgcn_global_load_lds( \
    (const __attribute__((address_space(1))) void*)(gp), \
    (__attribute__((address_space(3))) void*)(lp), 16, 0, 0)

// counted vmcnt wait (memory clobber: fences compiler code motion of LDS reads)
#define VMW(n) asm volatile("s_waitcnt vmcnt(" #n ")" ::: "memory")

// DPP row_shr add: accumulate toward higher lane within 16-lane row. Pure VALU.
template <int N>
__device__ __forceinline__ float dpp_shr_add(float x) {
  int xi = __builtin_bit_cast(int, x);
  int yi = __builtin_amdgcn_update_dpp(0, xi, 0x110 | N, 0xF, 0xF, true);
  return x + __builtin_bit_cast(float, yi);
}

// ---------------------------------------------------------------- cast x -> bf16
__global__ __launch_bounds__(256) void cast_x_kernel(const float* __restrict__ x,
                                                     short* __restrict__ xb) {
  const int i = blockIdx.x * 256 + threadIdx.x;   // float4 index
  float4v v = *(const float4v*)(x + (size_t)i * 4);
  short4v o;
  o[0] = (short)f2bf(v[0]); o[1] = (short)f2bf(v[1]);
  o[2] = (short)f2bf(v[2]); o[3] = (short)f2bf(v[3]);
  *(short4v*)(xb + (size_t)i * 4) = o;
}

// ---------------------------------------------- transpose+cast weights: T[n][k] = W[k][n]
__global__ __launch_bounds__(256) void transpose_cast_kernel(
    const float* __restrict__ W0, const float* __restrict__ W1,
    const float* __restrict__ W2, const float* __restrict__ W3,
    short* __restrict__ T0, short* __restrict__ T1,
    short* __restrict__ T2, short* __restrict__ T3) {
  __shared__ float tile[32][33];
  const float* W; short* T;
  switch (blockIdx.z) {
    case 0:  W = W0; T = T0; break;
    case 1:  W = W1; T = T1; break;
    case 2:  W = W2; T = T2; break;
    default: W = W3; T = T3; break;
  }
  const int t  = threadIdx.x;
  const int r  = t >> 3;          // 0..31
  const int c4 = (t & 7) * 4;     // 0,4,..28
  const int r0 = blockIdx.y * 32, c0 = blockIdx.x * 32;

  float4v v = *(const float4v*)(W + (size_t)(r0 + r) * K_ + c0 + c4);
  tile[r][c4 + 0] = v[0]; tile[r][c4 + 1] = v[1];
  tile[r][c4 + 2] = v[2]; tile[r][c4 + 3] = v[3];
  __syncthreads();
  short4v o;
#pragma unroll
  for (int j = 0; j < 4; ++j) o[j] = (short)f2bf(tile[c4 + j][r]);
  *(short4v*)(T + (size_t)(c0 + r) * K_ + r0 + c4) = o;
}

// ---------------------------------------------------------------- 256^2 phase-split GEMM
// C[m][n] = sum_k A[m][k] * Bt[n][k].  BM=BN=256, BK=32, 512 thr = 8 waves (2M x 4N),
// per-wave output 128x64 (acc[8][4] 16x16 frags). Double-buffered K-tiles (2 x 32KB LDS).
// LDS layout: per K-tile buffer: A.h0 | A.h1 | B.h0 | B.h1 (8KB each = 8 subtiles of
// 1024B, subtile = 16 rows x 32 cols bf16). st_16x32 swizzle: within a subtile, rows
// with (r&8) store cols XOR 16 — applied as inverse-swizzled GLOBAL source (gload dest
// is linear, rule both-sides-or-neither) + swizzled ds_read offset. Counted vmcnt(4)
// via inline asm + raw s_barrier (no __syncthreads => no compiler vmcnt(0) drain);
// each K-tile's 4 gloads get ~2 phases of compute cover. setprio(1) around MFMA.
// QFI=true: Bt rows = [Wq^T | Wf^T | Wi^T]; epilogue by n0 segment:
//   seg0: swish(acc)*DK^-0.5 -> C0   seg1: sigmoid(acc) -> C1   seg2: acc -> C2
template <bool QFI>
__global__ __launch_bounds__(512) void gemm8p(const short* __restrict__ A,
                                              const short* __restrict__ Bt,
                                              float* __restrict__ C0,
                                              float* __restrict__ C1,
                                              float* __restrict__ C2) {
  __shared__ __align__(16) char lds[65536];   // 2 buffers x 32KB
  const int t    = threadIdx.x;
  const int lane = t & 63;
  const int w    = t >> 6;           // wave 0..7
  const int l15  = lane & 15, l4 = lane >> 4;
  const int wm   = w >> 2, wn = w & 3;

  // XCD-aware bijective swizzle (grid % 8 == 0 for both instantiations)
  const int NBN = QFI ? 24 : 8;
  const int nwg = NBN * 32;
  const int bid = blockIdx.x;
  const int swz = (bid & 7) * (nwg >> 3) + (bid >> 3);
  const int bm  = swz / NBN, bn = swz - bm * NBN;
  const int m0  = bm * 256, n0 = bn * 256;

  // ---- staging addresses: wave w fills subtile sr=w of each half-tile.
  // lane l covers bytes [l*16, l*16+16) of the subtile: r = l>>2, phys col (l&3)*8.
  // inverse-swizzle the SOURCE col so that swizzled reads retrieve correct data.
  const int colx = ((lane & 3) * 8) ^ ((lane & 32) ? 16 : 0);
  const size_t arow = (size_t)(m0 + w * 16 + (lane >> 2)) * K_ + colx;
  const size_t brow = (size_t)(n0 + w * 16 + (lane >> 2)) * K_ + colx;
  char* const ldsw = lds + w * 1024;

  // ---- fragment-read offset within a subtile (swizzled)
  const int fragoff = l15 * 64 + ((l4 * 16) ^ ((l15 & 8) ? 32 : 0));
  const char* const aBase = lds + wm * 8192 + fragoff;                       // A half = wm
  const char* const bBase = lds + 16384 + (wn >> 1) * 8192 + (wn & 1) * 4096 + fragoff;

  float4v acc[8][4];
#pragma unroll
  for (int m = 0; m < 8; ++m)
#pragma unroll
    for (int n = 0; n < 4; ++n) acc[m][n] = float4v{0.f, 0.f, 0.f, 0.f};

  auto stage = [&](int buf, int kel) {     // kel = k offset in elements
    char* d = ldsw + buf * 32768;
    GLDS16(A  + arow + kel,            d);             // A.h0
    GLDS16(A  + arow + 128 * K_ + kel, d + 8192);      // A.h1
    GLDS16(Bt + brow + kel,            d + 16384);     // B.h0
    GLDS16(Bt + brow + 128 * K_ + kel, d + 24576);     // B.h1
  };

  short8v af[4], bf[4];
  auto ktile = [&](int buf) {
    const char* ab = aBase + buf * 32768;
    const char* bb = bBase + buf * 32768;
    // phase 1: m-frags 0..3 x all n
#pragma unroll
    for (int m = 0; m < 4; ++m) af[m] = *(const short8v*)(ab + m * 1024);
#pragma unroll
    for (int n = 0; n < 4; ++n) bf[n] = *(const short8v*)(bb + n * 1024);
    __builtin_amdgcn_s_barrier();
    __builtin_amdgcn_s_setprio(1);
#pragma unroll
    for (int m = 0; m < 4; ++m)
#pragma unroll
      for (int n = 0; n < 4; ++n)
        acc[m][n] = __builtin_amdgcn_mfma_f32_16x16x32_bf16(af[m], bf[n], acc[m][n], 0, 0, 0);
    __builtin_amdgcn_s_setprio(0);
    __builtin_amdgcn_s_barrier();
    // phase 2: m-frags 4..7 (B frags reused in regs)
#pragma unroll
    for (int m = 0; m < 4; ++m) af[m] = *(const short8v*)(ab + (4 + m) * 1024);
    __builtin_amdgcn_s_barrier();
    __builtin_amdgcn_s_setprio(1);
#pragma unroll
    for (int m = 0; m < 4; ++m)
#pragma unroll
      for (int n = 0; n < 4; ++n)
        acc[4 + m][n] = __builtin_amdgcn_mfma_f32_16x16x32_bf16(af[m], bf[n], acc[4 + m][n], 0, 0, 0);
    __builtin_amdgcn_s_setprio(0);
    __builtin_amdgcn_s_barrier();
  };

  // prologue: K-tiles 0,1 in flight; wait tile 0
  stage(0, 0);
  stage(1, 32);
  VMW(4);
  __builtin_amdgcn_s_barrier();

#pragma unroll 1
  for (int it = 0; it < 32; ++it) {
    const int kt = it * 2;
    ktile(0);                                        // compute K-tile kt (buf0)
    if (kt + 2 < 64) { stage(0, (kt + 2) * 32); VMW(4); } else VMW(0);
    __builtin_amdgcn_s_barrier();                    // buf1 (kt+1) ready
    ktile(1);
    if (kt + 3 < 64) { stage(1, (kt + 3) * 32); VMW(4); } else VMW(0);
    __builtin_amdgcn_s_barrier();                    // buf0 (kt+2) ready
  }

  // epilogue
  float* C; int ncol0, mode;
  if (QFI) {
    const int seg = n0 >> 11;
    C = (seg == 0) ? C0 : (seg == 1 ? C1 : C2);
    ncol0 = n0 & 2047;
    mode = seg;
  } else { C = C0; ncol0 = n0; mode = 2; }

#pragma unroll
  for (int m = 0; m < 8; ++m) {
#pragma unroll
    for (int n = 0; n < 4; ++n) {
#pragma unroll
      for (int jj = 0; jj < 4; ++jj) {
        const int row = m0 + wm * 128 + m * 16 + l4 * 4 + jj;  // C/D: col=lane&15, row=(lane>>4)*4+reg
        const int col = ncol0 + wn * 64 + n * 16 + l15;
        float val = acc[m][n][jj];
        if (mode == 0) {
          const float sg = 1.0f / (1.0f + __expf(-val));
          val = val * sg * 0.088388347648318447f;   // swish * DK^-0.5
        } else if (mode == 1) {
          val = 1.0f / (1.0f + __expf(-val));       // decay a = exp(log_sigmoid(f))
        }
        C[(size_t)row * 2048 + col] = val;
      }
    }
  }
}

// ---------------------------------------------------------------- recurrent scan v2
// Grid: 512 blocks = (b, head, dv-quarter 32). 256 threads: grp = t&7 (8 dk-groups
// of 16), dvl = t>>3 (32 dv cols). h[dk][dv] in regs (16/thread).
// Time chunks of T=16 steps, double-buffered LDS via global_load_lds.
#define TCHUNK 16
#define BUFSZ  18432   // 16*512 (q) + 16*512 (a) + 16*128 (v) bytes

__device__ __forceinline__ void stage_chunk(const float* __restrict__ q,
                                            const float* __restrict__ a,
                                            const float* __restrict__ v,
                                            char* buf, size_t bh, int qtr,
                                            int c0, int wv, int lane) {
  for (int i = wv; i < 18; i += 4) {        // wave-uniform trip count
    if (i < 8) {                            // q: instr i covers steps 2i,2i+1
      const float* g = q + bh + (size_t)(c0 + 2 * i + (lane >> 5)) * H_ + (lane & 31) * 4;
      GLDS16(g, buf + i * 1024);
    } else if (i < 16) {                    // a
      const int k = i - 8;
      const float* g = a + bh + (size_t)(c0 + 2 * k + (lane >> 5)) * H_ + (lane & 31) * 4;
      GLDS16(g, buf + 8192 + k * 1024);
    } else {                                // v: instr k covers steps 8k..8k+7
      const int k = i - 16;
      const float* g = v + bh + (size_t)(c0 + 8 * k + (lane >> 3)) * H_ + qtr * 32 + (lane & 7) * 4;
      GLDS16(g, buf + 16384 + k * 1024);
    }
  }
}

__global__ __launch_bounds__(256) void scan_kernel(const float* __restrict__ q,
                                                   const float* __restrict__ a,
                                                   const float* __restrict__ v,
                                                   float* __restrict__ o) {
  __shared__ __align__(16) char lds[2 * BUFSZ];
  const int blk  = blockIdx.x;
  const int qtr  = blk & 3;
  const int h    = (blk >> 2) & (NH_ - 1);
  const int b    = blk >> 6;
  const int t    = threadIdx.x;
  const int lane = t & 63;
  const int wv   = t >> 6;
  const int grp  = t & 7;
  const int dvl  = t >> 3;
  const int vcol = qtr * 32 + dvl;
  const size_t bh = (size_t)b * S_ * (size_t)H_ + (size_t)h * DK_;

  int qoff[4];
#pragma unroll
  for (int j = 0; j < 4; ++j) qoff[j] = grp * 64 + ((j ^ (grp & 3)) * 16);

  float hreg[16];
#pragma unroll
  for (int r = 0; r < 16; ++r) hreg[r] = 0.f;

  stage_chunk(q, a, v, lds, bh, qtr, 0, wv, lane);
  __syncthreads();   // drains vmcnt for chunk 0

  const int NCH = S_ / TCHUNK;   // 64
  for (int c = 0; c < NCH; ++c) {
    char* cur = lds + (c & 1) * BUFSZ;
    if (c + 1 < NCH)
      stage_chunk(q, a, v, lds + ((c & 1) ^ 1) * BUFSZ, bh, qtr, (c + 1) * TCHUNK, wv, lane);
    const int s0 = c * TCHUNK;
#pragma unroll
    for (int s = 0; s < TCHUNK; ++s) {
      float4v qv[4], av[4];
#pragma unroll
      for (int j = 0; j < 4; ++j) {
        qv[j] = *(const float4v*)(cur + s * 512 + qoff[j]);
        av[j] = *(const float4v*)(cur + 8192 + s * 512 + qoff[j]);
      }
      const float vv = *(const float*)(cur + 16384 + s * 128 + dvl * 4);
      float op = 0.f;
#pragma unroll
      for (int j = 0; j < 4; ++j) {
#pragma unroll
        for (int cc = 0; cc < 4; ++cc) {
          float& hr = hreg[j * 4 + cc];
          hr = fmaf(av[j][cc], hr - vv, vv);   // a*h + (1-a)*v
          op = fmaf(qv[j][cc], hr, op);
        }
      }
      op = dpp_shr_add<4>(op);
      op = dpp_shr_add<2>(op);
      op = dpp_shr_add<1>(op);
      if (grp == 7) o[bh + (size_t)(s0 + s) * H_ + vcol] = op;
    }
    __syncthreads();   // buf consumed; next-chunk loads drained
  }
}

// ---------------------------------------------------------------- rmsnorm -> bf16
__global__ __launch_bounds__(256) void rmsnorm_kernel(const float* __restrict__ ob,
                                                      const float* __restrict__ gw,
                                                      short* __restrict__ rb) {
  const int row = blockIdx.x;
  const int t   = threadIdx.x;
  const float* xr = ob + (size_t)row * 2048;
  float4v v0 = *(const float4v*)(xr + t * 4);
  float4v v1 = *(const float4v*)(xr + 1024 + t * 4);
  float ss = v0[0]*v0[0] + v0[1]*v0[1] + v0[2]*v0[2] + v0[3]*v0[3]
           + v1[0]*v1[0] + v1[1]*v1[1] + v1[2]*v1[2] + v1[3]*v1[3];
#pragma unroll
  for (int off = 32; off >= 1; off >>= 1) ss += __shfl_xor(ss, off);
  __shared__ float red[4];
  if ((t & 63) == 0) red[t >> 6] = ss;
  __syncthreads();
  const float tot = red[0] + red[1] + red[2] + red[3];
  const float sc  = rsqrtf(tot * (1.0f / 2048.0f) + 1e-5f);
  float4v g0 = *(const float4v*)(gw + t * 4);
  float4v g1 = *(const float4v*)(gw + 1024 + t * 4);
  short4v o0, o1;
#pragma unroll
  for (int j = 0; j < 4; ++j) {
    o0[j] = (short)f2bf(v0[j] * sc * g0[j]);
    o1[j] = (short)f2bf(v1[j] * sc * g1[j]);
  }
  *(short4v*)(rb + (size_t)row * 2048 + t * 4) = o0;
  *(short4v*)(rb + (size_t)row * 2048 + 1024 + t * 4) = o1;
}

// ---------------------------------------------------------------- launch
extern "C" void kernel_launch(void* const* d_in, const int* in_sizes, int n_in,
                              void* d_out, int out_size, void* d_ws, size_t ws_size,
                              hipStream_t stream) {
  const float* x  = (const float*)d_in[0];
  const float* Wq = (const float*)d_in[1];
  const float* Wf = (const float*)d_in[2];
  const float* Wi = (const float*)d_in[3];
  const float* Wo = (const float*)d_in[4];
  const float* gw = (const float*)d_in[5];

  // Workspace layout (256 MiB) with liveness-based aliasing:
  //   xb [0,32M)       bf16 x           -- dead after gemm_qfi; reused as rb
  //   WqT/WfT/WiT      [32M,56M) contiguous => [6144][2048] bf16 for fused gemm
  //   WoT [56M,64M)
  //   qb [64M,128M) ab [128M,192M) fp32
  //   vb [192M,256M)   fp32            -- scan overwrites in place with o (obuf)
  char* ws = (char*)d_ws;
  const size_t MB = 1024 * 1024;
  short* xb   = (short*)(ws);
  short* WqfiT= (short*)(ws + 32 * MB);
  short* WqT  = WqfiT;
  short* WfT  = (short*)(ws + 40 * MB);
  short* WiT  = (short*)(ws + 48 * MB);
  short* WoT  = (short*)(ws + 56 * MB);
  float* qb   = (float*)(ws + 64 * MB);
  float* ab   = (float*)(ws + 128 * MB);
  float* vb   = (float*)(ws + 192 * MB);
  float* obuf = vb;                       // alias: scan writes o over v in place
  short* rb   = xb;                       // alias: xb dead after gemm_qfi
  if (ws_size < 256 * MB) return;

  cast_x_kernel<<<(M_ * K_ / 4) / 256, 256, 0, stream>>>(x, xb);
  transpose_cast_kernel<<<dim3(K_ / 32, K_ / 32, 4), 256, 0, stream>>>(
      Wq, Wf, Wi, Wo, WqT, WfT, WiT, WoT);

  // fused q/f/i projection: N = 6144, 256^2 tiles -> 24x32 = 768 blocks
  gemm8p<true><<<768, 512, 0, stream>>>(xb, WqfiT, qb, ab, vb);

  scan_kernel<<<B_ * NH_ * 4, 256, 0, stream>>>(qb, ab, vb, obuf);
  rmsnorm_kernel<<<M_, 256, 0, stream>>>(obuf, gw, rb);

  // output projection: N = 2048 -> 8x32 = 256 blocks
  gemm8p<false><<<256, 512, 0, stream>>>(rb, WoT, (float*)d_out, nullptr, nullptr);
}